// Round 2
// baseline (11644.913 us; speedup 1.0000x reference)
//
#include <hip/hip_runtime.h>
#include <hip/hip_bf16.h>

#define NL 10000
#define NP 100000
#define PLEN 8
#define H 32
#define NROUNDS 8

typedef float f2 __attribute__((ext_vector_type(2)));

// ---------- ws layout (floats) ----------
// link_state: [0, 320000)
// path_state: [320000, 3520000)
// agg:        [3520000, 3840000)
// weights:    [3840000, 3853017)
// dtype flag: int at float-offset 3860000

__device__ __forceinline__ float bf2f(unsigned short u) {
  union { unsigned int i; float f; } v; v.i = ((unsigned int)u) << 16; return v.f;
}
__device__ __forceinline__ float sigm(float x) { return 1.f / (1.f + __expf(-x)); }
__device__ __forceinline__ float tanh_fast(float x) {
  x = fminf(15.f, fmaxf(-15.f, x));
  float e = __expf(2.f * x);
  return (e - 1.f) / (e + 1.f);
}
__device__ __forceinline__ float loadf(const void* p, long i, bool bf) {
  return bf ? bf2f(((const unsigned short*)p)[i]) : ((const float*)p)[i];
}

// ---------- dtype probe: are float inputs bf16 or fp32? ----------
// In bf16 mode each 32-bit word of link_capacity holds two bf16 values in
// [0,1): low ushort's high byte is ~always in [0x30,0x3F]. In fp32 mode the
// low ushort is uniform mantissa bits (~6% hit rate). Count over 256 words.
__global__ void probe_dtype(const unsigned int* __restrict__ cap_words,
                            int* __restrict__ flag) {
  if (threadIdx.x == 0 && blockIdx.x == 0) {
    int c = 0;
    for (int i = 0; i < 256; ++i) {
      unsigned int b = (cap_words[i] >> 8) & 0xFF;
      if (b >= 0x30 && b < 0x40) ++c;
    }
    *flag = (c > 128) ? 1 : 0;
  }
}

// GRU cell, everything in registers. W = [Wih|Whh|bih|bhh] fp32 block.
__device__ __forceinline__ void gru_cell_f2(const float* __restrict__ W,
                                            const f2 x[16], f2 h[16]) {
  const f2* Wih = (const f2*)W;           // [96][16]
  const f2* Whh = (const f2*)(W + 3072);  // [96][16]
  const float* bih = W + 6144;            // [96]
  const float* bhh = W + 6240;            // [96]
  f2 hn[16];
  #pragma unroll
  for (int jj = 0; jj < 16; ++jj) {
    #pragma unroll
    for (int s = 0; s < 2; ++s) {
      const int j = 2 * jj + s;
      f2 ar = {0.f, 0.f}, az = {0.f, 0.f}, an = {0.f, 0.f}, ah = {0.f, 0.f};
      #pragma unroll
      for (int k = 0; k < 16; ++k) {
        ar = __builtin_elementwise_fma(Wih[j * 16 + k], x[k], ar);
        ar = __builtin_elementwise_fma(Whh[j * 16 + k], h[k], ar);
        az = __builtin_elementwise_fma(Wih[(H + j) * 16 + k], x[k], az);
        az = __builtin_elementwise_fma(Whh[(H + j) * 16 + k], h[k], az);
        an = __builtin_elementwise_fma(Wih[(2 * H + j) * 16 + k], x[k], an);
        ah = __builtin_elementwise_fma(Whh[(2 * H + j) * 16 + k], h[k], ah);
      }
      float r = sigm(ar.x + ar.y + bih[j] + bhh[j]);
      float z = sigm(az.x + az.y + bih[H + j] + bhh[H + j]);
      float n = tanh_fast(an.x + an.y + bih[2 * H + j] +
                          r * (ah.x + ah.y + bhh[2 * H + j]));
      float hold = (s == 0) ? h[jj].x : h[jj].y;
      float hv = (1.f - z) * n + z * hold;
      if (s == 0) hn[jj].x = hv; else hn[jj].y = hv;
    }
  }
  #pragma unroll
  for (int k = 0; k < 16; ++k) h[k] = hn[k];
}

// ---------- weight conversion ----------
struct BfSeg { const void* src; int dstoff; int len; };
struct BfSegs { BfSeg s[14]; };

__global__ void convert_weights(BfSegs segs, const int* __restrict__ flag,
                                float* __restrict__ dst) {
  const bool bf = (*flag != 0);
  for (int si = 0; si < 14; ++si) {
    const void* p = segs.s[si].src;
    const int off = segs.s[si].dstoff, len = segs.s[si].len;
    for (int i = threadIdx.x; i < len; i += blockDim.x)
      dst[off + i] = loadf(p, i, bf);
  }
}

__global__ void init_states(const void* __restrict__ cap,
                            const void* __restrict__ bw,
                            const int* __restrict__ flag,
                            float* __restrict__ link_state,
                            float* __restrict__ path_state) {
  const bool bf = (*flag != 0);
  int i = blockIdx.x * blockDim.x + threadIdx.x;
  if (i < NP * H) path_state[i] = ((i & (H - 1)) == 0) ? loadf(bw, i >> 5, bf) : 0.f;
  if (i < NL * H) link_state[i] = ((i & (H - 1)) == 0) ? loadf(cap, i >> 5, bf) : 0.f;
}

// ---------- one message-passing round: path GRU over 8 hops ----------
__global__ __launch_bounds__(64) void path_round_kernel(
    const int* __restrict__ links, const float* __restrict__ link_state,
    float* __restrict__ path_state, float* __restrict__ agg,
    const float* __restrict__ W, int do_scatter) {
  int p = blockIdx.x * 64 + threadIdx.x;
  if (p >= NP) return;
  f2 h[16];
  const f2* ps2 = (const f2*)(path_state + (size_t)p * H);
  #pragma unroll
  for (int k = 0; k < 16; ++k) h[k] = ps2[k];
  int lk[PLEN];
  const int4* lp = (const int4*)(links + (size_t)p * PLEN);
  int4 la = lp[0], lb = lp[1];
  lk[0] = la.x; lk[1] = la.y; lk[2] = la.z; lk[3] = la.w;
  lk[4] = lb.x; lk[5] = lb.y; lk[6] = lb.z; lk[7] = lb.w;
  #pragma unroll 1
  for (int t = 0; t < PLEN; ++t) {
    const f2* xs = (const f2*)(link_state + (size_t)lk[t] * H);
    f2 x[16];
    #pragma unroll
    for (int k = 0; k < 16; ++k) x[k] = xs[k];
    gru_cell_f2(W, x, h);
    if (do_scatter) {
      float* dst = agg + (size_t)lk[t] * H;
      #pragma unroll
      for (int k = 0; k < 16; ++k) {
        unsafeAtomicAdd(dst + 2 * k, h[k].x);
        unsafeAtomicAdd(dst + 2 * k + 1, h[k].y);
      }
    }
  }
  f2* po = (f2*)(path_state + (size_t)p * H);
  #pragma unroll
  for (int k = 0; k < 16; ++k) po[k] = h[k];
}

__global__ __launch_bounds__(64) void link_round_kernel(
    const float* __restrict__ agg, float* __restrict__ link_state,
    const float* __restrict__ W) {
  int li = blockIdx.x * 64 + threadIdx.x;
  if (li >= NL) return;
  f2 x[16], h[16];
  const f2* xa = (const f2*)(agg + (size_t)li * H);
  f2* hs = (f2*)(link_state + (size_t)li * H);
  #pragma unroll
  for (int k = 0; k < 16; ++k) { x[k] = xa[k]; h[k] = hs[k]; }
  gru_cell_f2(W, x, h);
  #pragma unroll
  for (int k = 0; k < 16; ++k) hs[k] = h[k];
}

__global__ __launch_bounds__(256) void readout_kernel(
    const float* __restrict__ path_state, const float* __restrict__ W,
    const int* __restrict__ flag, void* __restrict__ out) {
  int p = blockIdx.x * 256 + threadIdx.x;
  if (p >= NP) return;
  const float* W1 = W;         // [8][32]
  const float* b1 = W + 256;   // [8]
  const float* W2 = W + 264;   // [8][8]
  const float* b2 = W + 328;   // [8]
  const float* W3 = W + 336;   // [8]
  const float* b3 = W + 344;   // [1]
  float xv[32];
  const float4* xp = (const float4*)(path_state + (size_t)p * H);
  #pragma unroll
  for (int k = 0; k < 8; ++k) {
    float4 v = xp[k];
    xv[4 * k] = v.x; xv[4 * k + 1] = v.y; xv[4 * k + 2] = v.z; xv[4 * k + 3] = v.w;
  }
  float y1[8];
  #pragma unroll
  for (int i = 0; i < 8; ++i) {
    float a = b1[i];
    #pragma unroll
    for (int k = 0; k < 32; ++k) a = fmaf(W1[i * 32 + k], xv[k], a);
    y1[i] = fmaxf(a, 0.f);
  }
  float y2[8];
  #pragma unroll
  for (int i = 0; i < 8; ++i) {
    float a = b2[i];
    #pragma unroll
    for (int k = 0; k < 8; ++k) a = fmaf(W2[i * 8 + k], y1[k], a);
    y2[i] = fmaxf(a, 0.f);
  }
  float o = b3[0];
  #pragma unroll
  for (int k = 0; k < 8; ++k) o = fmaf(W3[k], y2[k], o);
  if (*flag) ((__hip_bfloat16*)out)[p] = __float2bfloat16(o);
  else       ((float*)out)[p] = o;
}

extern "C" void kernel_launch(void* const* d_in, const int* in_sizes, int n_in,
                              void* d_out, int out_size, void* d_ws, size_t ws_size,
                              hipStream_t stream) {
  (void)in_sizes; (void)n_in; (void)out_size; (void)ws_size;
  const int* links = (const int*)d_in[0];
  // d_in[1]=paths, d_in[2]=seqs: structurally e=p*8+t (repeat/tile), unused.
  const void* cap = d_in[3];
  const void* bw  = d_in[4];

  float* ws = (float*)d_ws;
  float* link_state = ws;                // 320000
  float* path_state = ws + 320000;       // 3200000
  float* agg        = ws + 3520000;      // 320000
  float* wts        = ws + 3840000;      // 13017
  int*   flag       = (int*)(ws + 3860000);

  probe_dtype<<<1, 1, 0, stream>>>((const unsigned int*)cap, flag);

  BfSegs segs;
  const int srcidx[14] = {5, 6, 7, 8, 9, 10, 11, 12, 13, 14, 15, 16, 17, 18};
  const int offs[14]   = {0, 3072, 6144, 6240, 6336, 9408, 12480, 12576,
                          12672, 12928, 12936, 13000, 13008, 13016};
  const int lens[14]   = {3072, 3072, 96, 96, 3072, 3072, 96, 96,
                          256, 8, 64, 8, 8, 1};
  for (int i = 0; i < 14; ++i) {
    segs.s[i].src = d_in[srcidx[i]];
    segs.s[i].dstoff = offs[i];
    segs.s[i].len = lens[i];
  }
  convert_weights<<<1, 256, 0, stream>>>(segs, flag, wts);
  init_states<<<(NP * H + 255) / 256, 256, 0, stream>>>(cap, bw, flag, link_state, path_state);

  for (int r = 0; r < NROUNDS; ++r) {
    const int last = (r == NROUNDS - 1);
    if (!last) hipMemsetAsync(agg, 0, NL * H * sizeof(float), stream);
    path_round_kernel<<<(NP + 63) / 64, 64, 0, stream>>>(
        links, link_state, path_state, agg, wts, !last);
    if (!last)
      link_round_kernel<<<(NL + 63) / 64, 64, 0, stream>>>(agg, link_state, wts + 6336);
  }
  readout_kernel<<<(NP + 255) / 256, 256, 0, stream>>>(
      path_state, wts + 12672, flag, d_out);
}

// Round 3
// 5111.353 us; speedup vs baseline: 2.2782x; 2.2782x over previous
//
#include <hip/hip_runtime.h>
#include <hip/hip_bf16.h>

#define NL 10000
#define NP 100000
#define PLEN 8
#define H 32
#define NROUNDS 8
#define E_TOT (NP * PLEN)

typedef float f2 __attribute__((ext_vector_type(2)));

// ---------- ws layout (float offsets) ----------
#define LINK_OFF   0          // 320000
#define PATH_OFF   320000     // 3200000
#define AGG_OFF    3520000    // 320000
#define WTS_OFF    3840000    // 13344
#define FLAG_OFF   3860000    // 1
#define INT_OFF    3861000    // counts 10000 | offsets 10016 | cursor 10000 | edges 800000
#define HS_OFF     4700000    // 25600000
#define WS_NEED_FLOATS (HS_OFF + (size_t)E_TOT * H)   // 30,300,000 floats

__device__ __forceinline__ float bf2f(unsigned short u) {
  union { unsigned int i; float f; } v; v.i = ((unsigned int)u) << 16; return v.f;
}
__device__ __forceinline__ float sigm(float x) { return 1.f / (1.f + __expf(-x)); }
__device__ __forceinline__ float tanh_fast(float x) {
  x = fminf(15.f, fmaxf(-15.f, x));
  float e = __expf(2.f * x);
  return (e - 1.f) / (e + 1.f);
}
__device__ __forceinline__ float loadf(const void* p, long i, bool bf) {
  return bf ? bf2f(((const unsigned short*)p)[i]) : ((const float*)p)[i];
}

// ---------- dtype probe ----------
__global__ void probe_dtype(const unsigned int* __restrict__ cap_words,
                            int* __restrict__ flag) {
  if (threadIdx.x == 0 && blockIdx.x == 0) {
    int c = 0;
    for (int i = 0; i < 256; ++i) {
      unsigned int b = (cap_words[i] >> 8) & 0xFF;
      if (b >= 0x30 && b < 0x40) ++c;
    }
    *flag = (c > 128) ? 1 : 0;
  }
}

// ---------- GRU cell (fp32 registers) ----------
__device__ __forceinline__ void gru_cell_f2(const float* __restrict__ W,
                                            const f2 x[16], f2 h[16]) {
  const f2* Wih = (const f2*)W;           // [96][16]
  const f2* Whh = (const f2*)(W + 3072);  // [96][16]
  const float* bih = W + 6144;
  const float* bhh = W + 6240;
  f2 hn[16];
  #pragma unroll
  for (int jj = 0; jj < 16; ++jj) {
    #pragma unroll
    for (int s = 0; s < 2; ++s) {
      const int j = 2 * jj + s;
      f2 ar = {0.f, 0.f}, az = {0.f, 0.f}, an = {0.f, 0.f}, ah = {0.f, 0.f};
      #pragma unroll
      for (int k = 0; k < 16; ++k) {
        ar = __builtin_elementwise_fma(Wih[j * 16 + k], x[k], ar);
        ar = __builtin_elementwise_fma(Whh[j * 16 + k], h[k], ar);
        az = __builtin_elementwise_fma(Wih[(H + j) * 16 + k], x[k], az);
        az = __builtin_elementwise_fma(Whh[(H + j) * 16 + k], h[k], az);
        an = __builtin_elementwise_fma(Wih[(2 * H + j) * 16 + k], x[k], an);
        ah = __builtin_elementwise_fma(Whh[(2 * H + j) * 16 + k], h[k], ah);
      }
      float r = sigm(ar.x + ar.y + bih[j] + bhh[j]);
      float z = sigm(az.x + az.y + bih[H + j] + bhh[H + j]);
      float n = tanh_fast(an.x + an.y + bih[2 * H + j] +
                          r * (ah.x + ah.y + bhh[2 * H + j]));
      float hold = (s == 0) ? h[jj].x : h[jj].y;
      float hv = (1.f - z) * n + z * hold;
      if (s == 0) hn[jj].x = hv; else hn[jj].y = hv;
    }
  }
  #pragma unroll
  for (int k = 0; k < 16; ++k) h[k] = hn[k];
}

// ---------- weight conversion ----------
struct BfSeg { const void* src; int dstoff; int len; };
struct BfSegs { BfSeg s[14]; };

__global__ void convert_weights(BfSegs segs, const int* __restrict__ flag,
                                float* __restrict__ dst) {
  const bool bf = (*flag != 0);
  for (int si = 0; si < 14; ++si) {
    const void* p = segs.s[si].src;
    const int off = segs.s[si].dstoff, len = segs.s[si].len;
    for (int i = threadIdx.x; i < len; i += blockDim.x)
      dst[off + i] = loadf(p, i, bf);
  }
}

__global__ void init_states(const void* __restrict__ cap,
                            const void* __restrict__ bw,
                            const int* __restrict__ flag,
                            float* __restrict__ link_state,
                            float* __restrict__ path_state) {
  const bool bf = (*flag != 0);
  int i = blockIdx.x * blockDim.x + threadIdx.x;
  if (i < NP * H) path_state[i] = ((i & (H - 1)) == 0) ? loadf(bw, i >> 5, bf) : 0.f;
  if (i < NL * H) link_state[i] = ((i & (H - 1)) == 0) ? loadf(cap, i >> 5, bf) : 0.f;
}

// ---------- CSR build (once per call; graph fixed across rounds) ----------
__global__ void csr_count(const int* __restrict__ links, int* __restrict__ counts) {
  int e = blockIdx.x * blockDim.x + threadIdx.x;
  if (e < E_TOT) atomicAdd(&counts[links[e]], 1);
}

__global__ __launch_bounds__(256) void csr_scan(const int* __restrict__ counts,
                                                int* __restrict__ offsets,
                                                int* __restrict__ cursor) {
  __shared__ int part[256];
  const int t = threadIdx.x;
  const int base = t * 40;
  int s = 0;
  for (int i = 0; i < 40; ++i) {
    int idx = base + i;
    if (idx < NL) s += counts[idx];
  }
  part[t] = s;
  __syncthreads();
  for (int d = 1; d < 256; d <<= 1) {
    int v = (t >= d) ? part[t - d] : 0;
    __syncthreads();
    part[t] += v;
    __syncthreads();
  }
  int run = (t > 0) ? part[t - 1] : 0;
  for (int i = 0; i < 40; ++i) {
    int idx = base + i;
    if (idx < NL) {
      offsets[idx] = run;
      cursor[idx] = run;
      run += counts[idx];
    }
  }
  if (t == 255) offsets[NL] = run;
}

__global__ void csr_fill(const int* __restrict__ links, int* __restrict__ cursor,
                         int* __restrict__ edges) {
  int e = blockIdx.x * blockDim.x + threadIdx.x;
  if (e < E_TOT) {
    int l = links[e];
    int pos = atomicAdd(&cursor[l], 1);
    edges[pos] = e;  // e = p*PLEN + t indexes hs rows directly
  }
}

// ---------- path GRU round: gather-variant (stores hop messages, no atomics) ----------
__global__ __launch_bounds__(256) void path_round_gather(
    const int* __restrict__ links, const float* __restrict__ link_state,
    float* __restrict__ path_state, float* __restrict__ hs,
    const float* __restrict__ W, int store_msgs) {
  int p = blockIdx.x * 256 + threadIdx.x;
  if (p >= NP) return;
  f2 h[16];
  const f2* ps2 = (const f2*)(path_state + (size_t)p * H);
  #pragma unroll
  for (int k = 0; k < 16; ++k) h[k] = ps2[k];
  int lk[PLEN];
  const int4* lp = (const int4*)(links + (size_t)p * PLEN);
  int4 la = lp[0], lb = lp[1];
  lk[0] = la.x; lk[1] = la.y; lk[2] = la.z; lk[3] = la.w;
  lk[4] = lb.x; lk[5] = lb.y; lk[6] = lb.z; lk[7] = lb.w;
  f2 x[16];
  {
    const f2* xs = (const f2*)(link_state + (size_t)lk[0] * H);
    #pragma unroll
    for (int k = 0; k < 16; ++k) x[k] = xs[k];
  }
  #pragma unroll 1
  for (int t = 0; t < PLEN; ++t) {
    f2 xn[16];
    if (t + 1 < PLEN) {  // prefetch next hop's input while computing this one
      const f2* xs = (const f2*)(link_state + (size_t)lk[t + 1] * H);
      #pragma unroll
      for (int k = 0; k < 16; ++k) xn[k] = xs[k];
    }
    gru_cell_f2(W, x, h);
    if (store_msgs) {
      f2* o = (f2*)(hs + ((size_t)p * PLEN + t) * H);
      #pragma unroll
      for (int k = 0; k < 16; ++k) o[k] = h[k];
    }
    if (t + 1 < PLEN) {
      #pragma unroll
      for (int k = 0; k < 16; ++k) x[k] = xn[k];
    }
  }
  f2* po = (f2*)(path_state + (size_t)p * H);
  #pragma unroll
  for (int k = 0; k < 16; ++k) po[k] = h[k];
}

// ---------- per-link message aggregation: one wave per link, pure gather ----------
__global__ __launch_bounds__(256) void agg_gather(
    const int* __restrict__ offsets, const int* __restrict__ edges,
    const float* __restrict__ hs, float* __restrict__ agg) {
  int wave = (blockIdx.x * 256 + threadIdx.x) >> 6;
  int lane = threadIdx.x & 63;
  if (wave >= NL) return;
  const int beg = offsets[wave], end = offsets[wave + 1];
  const int elem = lane & 31, half = lane >> 5;
  float s = 0.f;
  for (int i = beg + half; i < end; i += 2) {
    int e = edges[i];
    s += hs[(size_t)e * H + elem];
  }
  s += __shfl_down(s, 32);
  if (lane < 32) agg[(size_t)wave * H + elem] = s;
}

// ---------- legacy atomic-scatter path kernel (fallback if ws too small) ----------
__global__ __launch_bounds__(64) void path_round_atomic(
    const int* __restrict__ links, const float* __restrict__ link_state,
    float* __restrict__ path_state, float* __restrict__ agg,
    const float* __restrict__ W, int do_scatter) {
  int p = blockIdx.x * 64 + threadIdx.x;
  if (p >= NP) return;
  f2 h[16];
  const f2* ps2 = (const f2*)(path_state + (size_t)p * H);
  #pragma unroll
  for (int k = 0; k < 16; ++k) h[k] = ps2[k];
  int lk[PLEN];
  const int4* lp = (const int4*)(links + (size_t)p * PLEN);
  int4 la = lp[0], lb = lp[1];
  lk[0] = la.x; lk[1] = la.y; lk[2] = la.z; lk[3] = la.w;
  lk[4] = lb.x; lk[5] = lb.y; lk[6] = lb.z; lk[7] = lb.w;
  #pragma unroll 1
  for (int t = 0; t < PLEN; ++t) {
    const f2* xs = (const f2*)(link_state + (size_t)lk[t] * H);
    f2 x[16];
    #pragma unroll
    for (int k = 0; k < 16; ++k) x[k] = xs[k];
    gru_cell_f2(W, x, h);
    if (do_scatter) {
      float* dst = agg + (size_t)lk[t] * H;
      #pragma unroll
      for (int k = 0; k < 16; ++k) {
        unsafeAtomicAdd(dst + 2 * k, h[k].x);
        unsafeAtomicAdd(dst + 2 * k + 1, h[k].y);
      }
    }
  }
  f2* po = (f2*)(path_state + (size_t)p * H);
  #pragma unroll
  for (int k = 0; k < 16; ++k) po[k] = h[k];
}

__global__ __launch_bounds__(64) void link_round_kernel(
    const float* __restrict__ agg, float* __restrict__ link_state,
    const float* __restrict__ W) {
  int li = blockIdx.x * 64 + threadIdx.x;
  if (li >= NL) return;
  f2 x[16], h[16];
  const f2* xa = (const f2*)(agg + (size_t)li * H);
  f2* hs = (f2*)(link_state + (size_t)li * H);
  #pragma unroll
  for (int k = 0; k < 16; ++k) { x[k] = xa[k]; h[k] = hs[k]; }
  gru_cell_f2(W, x, h);
  #pragma unroll
  for (int k = 0; k < 16; ++k) hs[k] = h[k];
}

__global__ __launch_bounds__(256) void readout_kernel(
    const float* __restrict__ path_state, const float* __restrict__ W,
    const int* __restrict__ flag, void* __restrict__ out) {
  int p = blockIdx.x * 256 + threadIdx.x;
  if (p >= NP) return;
  const float* W1 = W;
  const float* b1 = W + 256;
  const float* W2 = W + 264;
  const float* b2 = W + 328;
  const float* W3 = W + 336;
  const float* b3 = W + 344;
  float xv[32];
  const float4* xp = (const float4*)(path_state + (size_t)p * H);
  #pragma unroll
  for (int k = 0; k < 8; ++k) {
    float4 v = xp[k];
    xv[4 * k] = v.x; xv[4 * k + 1] = v.y; xv[4 * k + 2] = v.z; xv[4 * k + 3] = v.w;
  }
  float y1[8];
  #pragma unroll
  for (int i = 0; i < 8; ++i) {
    float a = b1[i];
    #pragma unroll
    for (int k = 0; k < 32; ++k) a = fmaf(W1[i * 32 + k], xv[k], a);
    y1[i] = fmaxf(a, 0.f);
  }
  float y2[8];
  #pragma unroll
  for (int i = 0; i < 8; ++i) {
    float a = b2[i];
    #pragma unroll
    for (int k = 0; k < 8; ++k) a = fmaf(W2[i * 8 + k], y1[k], a);
    y2[i] = fmaxf(a, 0.f);
  }
  float o = b3[0];
  #pragma unroll
  for (int k = 0; k < 8; ++k) o = fmaf(W3[k], y2[k], o);
  if (*flag) ((__hip_bfloat16*)out)[p] = __float2bfloat16(o);
  else       ((float*)out)[p] = o;
}

extern "C" void kernel_launch(void* const* d_in, const int* in_sizes, int n_in,
                              void* d_out, int out_size, void* d_ws, size_t ws_size,
                              hipStream_t stream) {
  (void)in_sizes; (void)n_in; (void)out_size;
  const int* links = (const int*)d_in[0];
  const void* cap = d_in[3];
  const void* bw  = d_in[4];

  float* ws = (float*)d_ws;
  float* link_state = ws + LINK_OFF;
  float* path_state = ws + PATH_OFF;
  float* agg        = ws + AGG_OFF;
  float* wts        = ws + WTS_OFF;
  int*   flag       = (int*)(ws + FLAG_OFF);
  int*   ibase      = (int*)(ws + INT_OFF);
  int*   counts     = ibase;             // 10000
  int*   offsets    = ibase + 10000;     // 10001 (padded 10016)
  int*   cursor     = ibase + 20016;     // 10000
  int*   edges      = ibase + 30016;     // 800000
  float* hs         = ws + HS_OFF;       // 25.6M floats

  const bool use_gather = ws_size >= WS_NEED_FLOATS * sizeof(float);

  probe_dtype<<<1, 1, 0, stream>>>((const unsigned int*)cap, flag);

  BfSegs segs;
  const int srcidx[14] = {5, 6, 7, 8, 9, 10, 11, 12, 13, 14, 15, 16, 17, 18};
  const int offs[14]   = {0, 3072, 6144, 6240, 6336, 9408, 12480, 12576,
                          12672, 12928, 12936, 13000, 13008, 13016};
  const int lens[14]   = {3072, 3072, 96, 96, 3072, 3072, 96, 96,
                          256, 8, 64, 8, 8, 1};
  for (int i = 0; i < 14; ++i) {
    segs.s[i].src = d_in[srcidx[i]];
    segs.s[i].dstoff = offs[i];
    segs.s[i].len = lens[i];
  }
  convert_weights<<<1, 256, 0, stream>>>(segs, flag, wts);
  init_states<<<(NP * H + 255) / 256, 256, 0, stream>>>(cap, bw, flag, link_state, path_state);

  if (use_gather) {
    hipMemsetAsync(counts, 0, NL * sizeof(int), stream);
    csr_count<<<(E_TOT + 255) / 256, 256, 0, stream>>>(links, counts);
    csr_scan<<<1, 256, 0, stream>>>(counts, offsets, cursor);
    csr_fill<<<(E_TOT + 255) / 256, 256, 0, stream>>>(links, cursor, edges);

    for (int r = 0; r < NROUNDS; ++r) {
      const int last = (r == NROUNDS - 1);
      path_round_gather<<<(NP + 255) / 256, 256, 0, stream>>>(
          links, link_state, path_state, hs, wts, !last);
      if (!last) {
        agg_gather<<<(NL * 64 + 255) / 256, 256, 0, stream>>>(offsets, edges, hs, agg);
        link_round_kernel<<<(NL + 63) / 64, 64, 0, stream>>>(agg, link_state, wts + 6336);
      }
    }
  } else {
    for (int r = 0; r < NROUNDS; ++r) {
      const int last = (r == NROUNDS - 1);
      if (!last) hipMemsetAsync(agg, 0, NL * H * sizeof(float), stream);
      path_round_atomic<<<(NP + 63) / 64, 64, 0, stream>>>(
          links, link_state, path_state, agg, wts, !last);
      if (!last)
        link_round_kernel<<<(NL + 63) / 64, 64, 0, stream>>>(agg, link_state, wts + 6336);
    }
  }
  readout_kernel<<<(NP + 255) / 256, 256, 0, stream>>>(
      path_state, wts + 12672, flag, d_out);
}